// Round 6
// baseline (404.314 us; speedup 1.0000x reference)
//
#include <hip/hip_runtime.h>
#include <hip/hip_bf16.h>
#include <math.h>

// Problem constants (match reference)
#define N_GRP 2048
#define LSLOT 64
#define NQ    4096
#define DIM   256
#define NTYPE 64
#define MMEM  131072
#define GSEG  16384
#define BEX   1024

// Workspace float-offsets
#define OFF_SEG   0u            // 16384*256 floats (16 MiB)
#define OFF_QW    4194304u      // 4096*256
#define OFF_MT    5242880u      // 256*256  (MT[j][i] = sum_z Wk[z][i]*Wq[z][j])
#define OFF_VB    5308416u      // 256      (vb[j] = sum_z Wq[z][j]*bk[z])
#define OFF_WB    5308672u      // 256      (wb[i] = sum_z Wk[z][i]*bq[z])
#define OFF_SB    5308928u      // 1  (sb = bq.bk), padded to 8
#define OFF_EM    5308936u      // 1024 ints
#define OFF_CNT   5309960u      // 1 int
#define OFF_NLL   5309964u      // 1 double (float offset 5309964*4 % 8 == 0)
#define OFF_FLAG  5309966u      // 1 int: bool-storage mode (0=int32,1=int8,2=f32)
#define OFF_CQ    5310208u      // 4096 floats: cq[q] = q.vb + sb
#define OFF_PTR   5314304u      // 16385 ints: CSR bounds for grp (guarded by ws_size)
#define WS_NEED_PTR ((size_t)(OFF_PTR + GSEG + 1) * 4)

// Output float-offsets: [0,262144) logit (staged as p first) ; acc ; emr ; nll ; em(1024)
#define OUT_ACC 262144
#define OUT_EMR 262145
#define OUT_NLL 262146
#define OUT_EM  262147

__device__ __forceinline__ bool rd_bool(const void* p, int i, int mode) {
  if (mode == 0) return ((const int*)p)[i] != 0;
  if (mode == 1) return ((const unsigned char*)p)[i] != 0;
  return ((const float*)p)[i] != 0.f;
}

// Precompute MT = Wk^T Wq (MT[j][i]), vb, wb, sb; bool-mode detect; em/cnt/nll
// init; CSR bounds ptr[] for sorted grp. 259 + 512 blocks x 256.
__global__ __launch_bounds__(256)
void k_pre(const float* __restrict__ Wq, const float* __restrict__ bq,
           const float* __restrict__ Wk, const float* __restrict__ bk,
           const void* __restrict__ typ, const int* __restrict__ grp,
           float* __restrict__ ws, int use_ptr) {
  int b = blockIdx.x, t = threadIdx.x;
  if (b < 256) {
    int j = b;
    float a0 = 0.f, a1 = 0.f, a2 = 0.f, a3 = 0.f;   // 4 chains for ILP
    for (int z = 0; z < 256; z += 4) {
      a0 += Wk[(z + 0) * 256 + t] * Wq[(z + 0) * 256 + j];
      a1 += Wk[(z + 1) * 256 + t] * Wq[(z + 1) * 256 + j];
      a2 += Wk[(z + 2) * 256 + t] * Wq[(z + 2) * 256 + j];
      a3 += Wk[(z + 3) * 256 + t] * Wq[(z + 3) * 256 + j];
    }
    ws[OFF_MT + (unsigned)j * 256 + t] = (a0 + a1) + (a2 + a3);
  } else if (b == 256) {
    float a = 0.f;
    #pragma unroll 8
    for (int z = 0; z < 256; ++z) a += Wq[z * 256 + t] * bk[z];
    ws[OFF_VB + t] = a;
  } else if (b == 257) {
    float a = 0.f;
    #pragma unroll 8
    for (int z = 0; z < 256; ++z) a += Wk[z * 256 + t] * bq[z];
    ws[OFF_WB + t] = a;
    __shared__ float red[256];
    red[t] = bq[t] * bk[t];
    __syncthreads();
    for (int st = 128; st; st >>= 1) { if (t < st) red[t] += red[t + st]; __syncthreads(); }
    if (t == 0) ws[OFF_SB] = red[0];
  } else if (b == 258) {
    // bool-mode detection + small-state init
    __shared__ int fl_f, fl_b;
    if (t == 0) { fl_f = 0; fl_b = 0; }
    __syncthreads();
    for (int i = t; i < 4096; i += 256) {
      unsigned wv = ((const unsigned*)typ)[i];
      if (wv == 0x3F800000u) atomicOr(&fl_f, 1);   // float32 1.0 pattern
      else if (wv > 1u)      atomicOr(&fl_b, 1);   // packed-byte pattern
    }
    __syncthreads();
    int* em = (int*)(ws + OFF_EM);
    for (int i = t; i < BEX; i += 256) em[i] = 0x7FFFFFFF;  // segment_min identity
    if (t == 0) {
      *(int*)(ws + OFF_FLAG) = fl_f ? 2 : (fl_b ? 1 : 0);
      *(int*)(ws + OFF_CNT) = 0;
      *(double*)(ws + OFF_NLL) = 0.0;
    }
  } else {
    // b in [259, 259+512): CSR bounds build. ptr[g] = first i with grp[i] >= g.
    if (!use_ptr) return;
    int i = (b - 259) * 256 + t;
    int gi = grp[i];
    int gp = (i == 0) ? -1 : grp[i - 1];
    int* ptr = (int*)(ws + OFF_PTR);
    for (int gg = gp + 1; gg <= gi; ++gg) ptr[gg] = i;
    if (i == MMEM - 1)
      for (int gg = gi + 1; gg <= GSEG; ++gg) ptr[gg] = MMEM;
  }
}

// Merged: blocks [0,4096) segment_sum; blocks [4096,4608) qw GEMV (+cq).
__global__ __launch_bounds__(256)
void k_segqw(const float* __restrict__ emb, const int* __restrict__ mem,
             const int* __restrict__ grp, const float* __restrict__ q,
             float* __restrict__ ws, int use_ptr) {
  int t = threadIdx.x;
  if (blockIdx.x < GSEG / 4) {
    // ---- segment_sum(emb[mem], grp) -> seg[G][256]; one WAVE per segment.
    int lane = t & 63, w = t >> 6;
    int g = blockIdx.x * 4 + w;
    int lo, lo2;
    if (use_ptr) {
      const int* ptr = (const int*)(ws + OFF_PTR);
      lo = ptr[g]; lo2 = ptr[g + 1];               // 2 scalar loads, no search
    } else {
      int l0 = 0, h0 = MMEM;
      while (l0 < h0) { int mid = (l0 + h0) >> 1; if (grp[mid] < g) l0 = mid + 1; else h0 = mid; }
      lo = l0; int l1 = l0, h1 = MMEM;
      while (l1 < h1) { int mid = (l1 + h1) >> 1; if (grp[mid] < g + 1) l1 = mid + 1; else h1 = mid; }
      lo2 = l1;
    }
    int n = lo2 - lo;
    int nv = n < 64 ? n : 64;
    int tok = (lane < nv) ? mem[lo + lane] : 0;    // one coalesced batch load
    float4 acc = {0.f, 0.f, 0.f, 0.f};
    int r = 0;
    for (; r + 4 <= nv; r += 4) {
      int t0 = __shfl(tok, r + 0), t1 = __shfl(tok, r + 1);
      int t2 = __shfl(tok, r + 2), t3 = __shfl(tok, r + 3);
      float4 v0 = *(const float4*)(emb + (size_t)t0 * 256 + lane * 4);
      float4 v1 = *(const float4*)(emb + (size_t)t1 * 256 + lane * 4);
      float4 v2 = *(const float4*)(emb + (size_t)t2 * 256 + lane * 4);
      float4 v3 = *(const float4*)(emb + (size_t)t3 * 256 + lane * 4);
      acc.x += (v0.x + v1.x) + (v2.x + v3.x);
      acc.y += (v0.y + v1.y) + (v2.y + v3.y);
      acc.z += (v0.z + v1.z) + (v2.z + v3.z);
      acc.w += (v0.w + v1.w) + (v2.w + v3.w);
    }
    for (; r < nv; ++r) {
      int tr = __shfl(tok, r);
      float4 v = *(const float4*)(emb + (size_t)tr * 256 + lane * 4);
      acc.x += v.x; acc.y += v.y; acc.z += v.z; acc.w += v.w;
    }
    for (int rr = lo + 64; rr < lo2; ++rr) {       // overflow fallback (P ~ 0)
      int tr = mem[rr];
      float4 v = *(const float4*)(emb + (size_t)tr * 256 + lane * 4);
      acc.x += v.x; acc.y += v.y; acc.z += v.z; acc.w += v.w;
    }
    *(float4*)(ws + OFF_SEG + (size_t)g * 256 + lane * 4) = acc;
  } else {
    // ---- qw[r] = MT^T q[r] + wb ; cq[r] = q[r].vb + sb ; 8 queries/block.
    int b = blockIdx.x - GSEG / 4;
    int r0 = b * 8;
    const float* MT = ws + OFF_MT;
    float acc[8], cq[8];
    float wbv = ws[OFF_WB + t];
    #pragma unroll
    for (int r = 0; r < 8; ++r) { acc[r] = wbv; cq[r] = 0.f; }
    for (int j = 0; j < 256; j += 4) {
      float m0 = MT[(j + 0) * 256 + t];
      float m1 = MT[(j + 1) * 256 + t];
      float m2 = MT[(j + 2) * 256 + t];
      float m3 = MT[(j + 3) * 256 + t];
      float4 vb4 = *(const float4*)(ws + OFF_VB + j);   // uniform
      #pragma unroll
      for (int r = 0; r < 8; ++r) {
        float4 q4 = *(const float4*)(q + (size_t)(r0 + r) * 256 + j);  // uniform
        acc[r] += q4.x * m0 + q4.y * m1 + q4.z * m2 + q4.w * m3;
        cq[r] += q4.x * vb4.x + q4.y * vb4.y + q4.z * vb4.z + q4.w * vb4.w;
      }
    }
    #pragma unroll
    for (int r = 0; r < 8; ++r) ws[OFF_QW + (unsigned)(r0 + r) * 256 + t] = acc[r];
    if (t == 0) {
      float sb = ws[OFF_SB];
      #pragma unroll
      for (int r = 0; r < 8; ++r) ws[OFF_CQ + r0 + r] = cq[r] + sb;  // all lanes equal
    }
  }
}

// Scores + softmax -> p staged in out[] (logit region, overwritten later).
// One block per group; quad (lane>>2)=slot, (lane&3)=dim-quad; masked slots
// predicated off (saves ~30% of k reads).
__global__ __launch_bounds__(256)
void k_score(const float* __restrict__ k, const void* __restrict__ mmask,
             float* __restrict__ ws, float* __restrict__ out) {
  int g = blockIdx.x, t = threadIdx.x;
  int lane = t & 63, w = t >> 6;
  __shared__ float qw_l[2][256];
  __shared__ float s_raw[2][64];
  const int q0 = 2 * g;
  const int mode = *(const int*)(ws + OFF_FLAG);

  qw_l[0][t] = ws[OFF_QW + (unsigned)q0 * 256 + t];
  qw_l[1][t] = ws[OFF_QW + (unsigned)(q0 + 1) * 256 + t];
  __syncthreads();

  {
    int sl = w * 16 + (lane >> 2);                 // slot 0..63
    int c4 = lane & 3;
    bool valid = rd_bool(mmask, g * LSLOT + sl, mode);
    if (valid) {                                   // per-quad predication
      const float* kr = k + (size_t)g * LSLOT * 256 + (size_t)sl * 256 + c4 * 4;
      float s0 = 0.f, s1 = 0.f;
      #pragma unroll
      for (int j = 0; j < 16; ++j) {
        float4 kv = *(const float4*)(kr + j * 16);
        float4 w0 = *(const float4*)&qw_l[0][j * 16 + c4 * 4];
        float4 w1 = *(const float4*)&qw_l[1][j * 16 + c4 * 4];
        s0 += kv.x * w0.x + kv.y * w0.y + kv.z * w0.z + kv.w * w0.w;
        s1 += kv.x * w1.x + kv.y * w1.y + kv.z * w1.z + kv.w * w1.w;
      }
      s0 += __shfl_xor(s0, 1); s0 += __shfl_xor(s0, 2);
      s1 += __shfl_xor(s1, 1); s1 += __shfl_xor(s1, 2);
      if (c4 == 0) { s_raw[0][sl] = s0; s_raw[1][sl] = s1; }
    }
  }
  __syncthreads();

  if (w < 2) {
    bool valid = rd_bool(mmask, g * LSLOT + lane, mode);
    float cq = ws[OFF_CQ + q0 + w];
    float v = valid ? (s_raw[w][lane] + cq) * 0.0625f : -INFINITY;
    float mx = v;
    for (int off = 32; off; off >>= 1) mx = fmaxf(mx, __shfl_xor(mx, off));
    float e = expf(v - mx);                        // -inf -> exactly 0
    float ssum = e;
    for (int off = 32; off; off >>= 1) ssum += __shfl_xor(ssum, off);
    out[(size_t)(q0 + w) * NTYPE + lane] = e / ssum;   // stage p in logit slot
  }
}

// att (seg gather) + logits + metrics. One block per group.
__global__ __launch_bounds__(256)
void k_attlogit(const float* __restrict__ q, const float* __restrict__ Wrel,
                const float* __restrict__ brel, const int* __restrict__ pos2grp,
                const void* __restrict__ typ, const int* __restrict__ idx,
                float* __restrict__ ws, float* __restrict__ out) {
  int g = blockIdx.x, t = threadIdx.x;
  int lane = t & 63, w = t >> 6;
  __shared__ float qr_l[2][256], att_l[2][256];
  __shared__ float p_l[2][64], lg_l[2][64];
  __shared__ float att_p[4][2][64][4];
  __shared__ float nll_l;
  __shared__ int eqcnt_l, all_l[2];
  const int q0 = 2 * g;
  const int mode = *(const int*)(ws + OFF_FLAG);

  qr_l[0][t] = q[(size_t)q0 * 256 + t];
  qr_l[1][t] = q[(size_t)(q0 + 1) * 256 + t];
  if (w < 2) p_l[w][lane] = out[(size_t)(q0 + w) * NTYPE + lane];  // staged p
  if (t == 0) { eqcnt_l = 0; nll_l = 0.f; }
  __syncthreads();

  // D: att[q][d] = sum_l p[q][l]*seg[pos2grp[g][l]][d]; wave w: l = 4*li+w.
  {
    float4 a0 = {0.f,0.f,0.f,0.f}, a1 = {0.f,0.f,0.f,0.f};
    const float* seg = ws + OFF_SEG;
    const int* pg = pos2grp + g * LSLOT;
    #pragma unroll 4
    for (int li = 0; li < 16; ++li) {
      int l = li * 4 + w;
      float p0 = p_l[0][l], p1 = p_l[1][l];
      if (p0 == 0.f && p1 == 0.f) continue;        // wave-uniform skip (masked)
      int row = pg[l];                             // wave-uniform -> scalar load
      float4 v = *(const float4*)(seg + (size_t)row * 256 + lane * 4);
      a0.x += p0 * v.x; a0.y += p0 * v.y; a0.z += p0 * v.z; a0.w += p0 * v.w;
      a1.x += p1 * v.x; a1.y += p1 * v.y; a1.z += p1 * v.z; a1.w += p1 * v.w;
    }
    *(float4*)&att_p[w][0][lane][0] = a0;
    *(float4*)&att_p[w][1][lane][0] = a1;
  }
  __syncthreads();
  {
    int dl = t >> 2, dc = t & 3;
    #pragma unroll
    for (int qi = 0; qi < 2; ++qi)
      att_l[qi][t] = att_p[0][qi][dl][dc] + att_p[1][qi][dl][dc]
                   + att_p[2][qi][dl][dc] + att_p[3][qi][dl][dc];
  }
  __syncthreads();

  // E: logit[q][tt] = [qrow|att].Wrel[tt] + brel[tt]; quad-mapped.
  {
    int qi = w >> 1;
    int c4 = lane & 3;
    #pragma unroll
    for (int h = 0; h < 2; ++h) {
      int tt = (w & 1) * 32 + h * 16 + (lane >> 2);
      const float* wr = Wrel + (size_t)tt * 512 + c4 * 4;
      float s = 0.f;
      #pragma unroll
      for (int j = 0; j < 16; ++j) {
        float4 wv = *(const float4*)(wr + j * 16);
        float4 xv = *(const float4*)&qr_l[qi][j * 16 + c4 * 4];
        s += wv.x * xv.x + wv.y * xv.y + wv.z * xv.z + wv.w * xv.w;
      }
      #pragma unroll
      for (int j = 0; j < 16; ++j) {
        float4 wv = *(const float4*)(wr + 1024 + j * 16);
        float4 xv = *(const float4*)&att_l[qi][j * 16 + c4 * 4];
        s += wv.x * xv.x + wv.y * xv.y + wv.z * xv.z + wv.w * xv.w;
      }
      s += __shfl_xor(s, 1); s += __shfl_xor(s, 2);
      if (c4 == 0) lg_l[qi][tt] = s;
    }
  }
  __syncthreads();

  // Stats: waves 0,1 (qi=w), lane=tt. Coalesced logit store + ballot stats.
  if (w < 2) {
    int qi = w;
    float lg = lg_l[qi][lane] + brel[lane];
    out[(size_t)(q0 + qi) * NTYPE + lane] = lg;    // overwrite staged p
    bool gt = lg > 0.f;
    bool tv = rd_bool(typ, (q0 + qi) * NTYPE + lane, mode);
    bool eqv = (gt == tv);
    unsigned long long mask = __ballot(eqv);
    float nllp = fmaxf(lg, 0.f) + log1pf(expf(-fabsf(lg))) - (tv ? lg : 0.f);
    for (int off = 32; off; off >>= 1) nllp += __shfl_xor(nllp, off);
    if (lane == 0) {
      all_l[qi] = (mask == 0xFFFFFFFFFFFFFFFFull) ? 1 : 0;
      atomicAdd(&eqcnt_l, (int)__popcll(mask));
      atomicAdd(&nll_l, nllp);
    }
  }
  __syncthreads();
  if (t == 0) {
    atomicAdd((int*)(ws + OFF_CNT), eqcnt_l);
    atomicAdd((double*)(ws + OFF_NLL), (double)nll_l);
    int* em = (int*)(ws + OFF_EM);
    atomicMin(&em[idx[q0]], all_l[0]);
    atomicMin(&em[idx[q0 + 1]], all_l[1]);
  }
}

__global__ __launch_bounds__(256)
void k_fin(float* __restrict__ ws, float* __restrict__ out) {
  __shared__ float red[256];
  int t = threadIdx.x;
  const int* em = (const int*)(ws + OFF_EM);
  float s = 0.f;
  for (int i = t; i < BEX; i += 256) {
    float v = (float)em[i];
    out[OUT_EM + i] = v;
    s += v;
  }
  red[t] = s; __syncthreads();
  for (int st = 128; st; st >>= 1) { if (t < st) red[t] += red[t + st]; __syncthreads(); }
  if (t == 0) {
    out[OUT_ACC] = (float)(*(const int*)(ws + OFF_CNT)) / (float)(NQ * NTYPE);
    out[OUT_EMR] = red[0] / (float)BEX;
    out[OUT_NLL] = (float)((*(const double*)(ws + OFF_NLL)) / (double)N_GRP);
  }
}

extern "C" void kernel_launch(void* const* d_in, const int* in_sizes, int n_in,
                              void* d_out, int out_size, void* d_ws, size_t ws_size,
                              hipStream_t stream) {
  const float* q    = (const float*)d_in[0];
  const float* k    = (const float*)d_in[1];
  const float* emb  = (const float*)d_in[2];
  const float* Wq   = (const float*)d_in[3];
  const float* bq   = (const float*)d_in[4];
  const float* Wk   = (const float*)d_in[5];
  const float* bk   = (const float*)d_in[6];
  const float* Wrel = (const float*)d_in[7];
  const float* brel = (const float*)d_in[8];
  const void* mmask   = d_in[9];           // bool m (mode-detected)
  // d_in[10] = qgrp: deterministic repeat_interleave(arange(N_GRP), 2) -> q0 = 2*g
  const int* mem      = (const int*)d_in[11];
  const int* grp      = (const int*)d_in[12];
  const int* pos2grp  = (const int*)d_in[13];
  const void* typ     = d_in[14];          // bool typ (mode-detected)
  const int* idx      = (const int*)d_in[15];
  float* ws  = (float*)d_ws;
  float* out = (float*)d_out;
  int use_ptr = (ws_size >= WS_NEED_PTR) ? 1 : 0;

  k_pre     <<<259 + MMEM/256, 256, 0, stream>>>(Wq, bq, Wk, bk, typ, grp, ws, use_ptr);
  k_segqw   <<<GSEG/4 + NQ/8,  256, 0, stream>>>(emb, mem, grp, q, ws, use_ptr);
  k_score   <<<N_GRP,          256, 0, stream>>>(k, mmask, ws, out);
  k_attlogit<<<N_GRP,          256, 0, stream>>>(q, Wrel, brel, pos2grp, typ, idx, ws, out);
  k_fin     <<<1,              256, 0, stream>>>(ws, out);
}